// Round 2
// baseline (259.546 us; speedup 1.0000x reference)
//
#include <hip/hip_runtime.h>

// Integrate-and-fire scan: x_seq (T=64, 128, 4096) f32 -> s_seq same shape.
//   v += x[t]; s = (v >= 1.0f); v -= s;
//
// ROUND-2 PROBE: kernel body is IDENTICAL to round 1 (best known: 228 us).
// We launch it TWICE back-to-back in the same stream. The computation is
// deterministic and idempotent, so output is bit-identical and the test
// still passes. Purpose: dur_us(2x) - dur_us(1x) = the kernel's true
// marginal duration, which rocprof has never shown us (our dispatch is
// absent from top-5 in both rounds -> its dur < 79 us, while dur_us=226-228
// stays constant across 4 independent kernel-axis changes: NT<->cached
// stores, float2<->float4, 16<->8 waves/CU, pipeline depth 1<->8).
// Pre-committed reading:
//   delta ~ 40-80 us  -> kernel at memory floor, dur_us is harness-dominated,
//                        next round: revert to single launch, declare roofline.
//   delta >= 150 us   -> kernel genuinely slow; next round: column-swizzled
//                        traversal to break 2 MiB-stride DRAM resonance.

#define TSTEPS 64
#define NCOLS  (128 * 4096)    // 524288 columns
#define NCOLS4 (NCOLS / 4)     // 131072 float4 column-groups, 2 MiB time stride
#define BATCH  4               // float4 loads in flight per wave (64 B/lane)

__global__ __launch_bounds__(256) void TandemIF_86096914416163_kernel(
    const float4* __restrict__ x, float4* __restrict__ out)
{
    const int c = blockIdx.x * 256 + threadIdx.x;   // grid sized exactly
    const float4* xp = x   + c;
    float4*       op = out + c;

    float vx = 0.0f, vy = 0.0f, vz = 0.0f, vw = 0.0f;
    float4 buf[2][BATCH];

    // Prime the pipeline: batch 0 in flight.
#pragma unroll
    for (int j = 0; j < BATCH; ++j)
        buf[0][j] = xp[j * NCOLS4];

    // Fully unrolled outer loop -> buffers stay in registers, ping-pong static.
#pragma unroll
    for (int tb = 0; tb < TSTEPS / BATCH; ++tb) {
        const int cur = tb & 1, nxt = cur ^ 1;

        // Issue next batch's loads BEFORE consuming current batch: vmcnt
        // retires in order, these sit BEHIND the current batch in the queue,
        // so waiting on cur[j] never waits on them.
        if (tb < TSTEPS / BATCH - 1) {
#pragma unroll
            for (int j = 0; j < BATCH; ++j)
                buf[nxt][j] = xp[((tb + 1) * BATCH + j) * NCOLS4];
        }

#pragma unroll
        for (int j = 0; j < BATCH; ++j) {
            const float4 xt = buf[cur][j];
            vx += xt.x; vy += xt.y; vz += xt.z; vw += xt.w;
            const float sx = (vx >= 1.0f) ? 1.0f : 0.0f;
            const float sy = (vy >= 1.0f) ? 1.0f : 0.0f;
            const float sz = (vz >= 1.0f) ? 1.0f : 0.0f;
            const float sw = (vw >= 1.0f) ? 1.0f : 0.0f;
            vx -= sx; vy -= sy; vz -= sz; vw -= sw;
            op[(tb * BATCH + j) * NCOLS4] = make_float4(sx, sy, sz, sw);
        }
    }
}

extern "C" void kernel_launch(void* const* d_in, const int* in_sizes, int n_in,
                              void* d_out, int out_size, void* d_ws, size_t ws_size,
                              hipStream_t stream)
{
    const float4* x = (const float4*)d_in[0];
    float4* out     = (float4*)d_out;
    // 131072 float4 columns / 256 threads = 512 blocks (2 blocks/CU, 8 waves/CU)
    TandemIF_86096914416163_kernel<<<dim3(NCOLS4 / 256), dim3(256), 0, stream>>>(x, out);
    // PROBE: second identical launch. Idempotent -> output unchanged.
    // dur_us delta vs round 1 (228 us) = true marginal kernel time.
    TandemIF_86096914416163_kernel<<<dim3(NCOLS4 / 256), dim3(256), 0, stream>>>(x, out);
}

// Round 3
// 224.266 us; speedup vs baseline: 1.1573x; 1.1573x over previous
//
#include <hip/hip_runtime.h>
#include <string.h>

// Integrate-and-fire scan: x_seq (T=64, 128, 4096) f32 -> s_seq same shape.
//   v += x[t]; s = (v >= 1.0f); v -= s;
//
// FINAL (restored round-0 best, 226.1 us harness-verified).
//
// Session conclusion (round-2 probe, double-launch): marginal kernel time is
// 31 us L3-warm (259.5 - 228.3); cold time bracketed [40, 79] us (absent from
// every top-5 rocprof table whose floor row is 79 us). dur_us ~ 226 is
// ~190 us fixed harness cost (80 us / 536 MB poison fill at 6.7 TB/s + reset
// swarm). Ideal traffic 268 MB -> 40 us floor at 6.7 TB/s: the kernel is AT
// the memory roofline. This explains why NT<->cached stores, float2<->float4,
// 8<->16 waves/CU, and pipeline depth 1<->8 were all null within +-1%.

#define TSTEPS 64
#define NCOLS  (128 * 4096)    // 524288 columns
#define NCOLS2 (NCOLS / 2)     // 262144 float2 column-groups
#define BATCH  8               // loads in flight per wave

__global__ __launch_bounds__(256) void TandemIF_86096914416163_kernel(
    const float2* __restrict__ x, float2* __restrict__ out)
{
    const int c = blockIdx.x * 256 + threadIdx.x;   // grid sized exactly
    const float2* xp = x   + c;
    float2*       op = out + c;

    float vx = 0.0f, vy = 0.0f;
    float2 buf[2][BATCH];

    // Prime the pipeline: batch 0 in flight.
#pragma unroll
    for (int j = 0; j < BATCH; ++j)
        buf[0][j] = xp[j * NCOLS2];

    // Fully unrolled outer loop -> buffers stay in registers, ping-pong is static.
#pragma unroll
    for (int tb = 0; tb < TSTEPS / BATCH; ++tb) {
        const int cur = tb & 1, nxt = cur ^ 1;

        // Issue next batch's loads BEFORE touching current batch: since vmcnt
        // retires in order and these sit BEHIND the current batch in the queue,
        // waiting on cur[j] never waits on them -> 8 loads always outstanding.
        if (tb < TSTEPS / BATCH - 1) {
#pragma unroll
            for (int j = 0; j < BATCH; ++j)
                buf[nxt][j] = xp[((tb + 1) * BATCH + j) * NCOLS2];
        }

#pragma unroll
        for (int j = 0; j < BATCH; ++j) {
            const float2 xt = buf[cur][j];
            vx += xt.x; vy += xt.y;
            const float sx = (vx >= 1.0f) ? 1.0f : 0.0f;
            const float sy = (vy >= 1.0f) ? 1.0f : 0.0f;
            vx -= sx; vy -= sy;
            float2 s = make_float2(sx, sy);
            // Non-temporal 8B store: s is write-once/read-never; keep L2/L3 for x.
            double sbits;
            memcpy(&sbits, &s, sizeof(sbits));
            __builtin_nontemporal_store(
                sbits, reinterpret_cast<double*>(op + (tb * BATCH + j) * NCOLS2));
        }
    }
}

extern "C" void kernel_launch(void* const* d_in, const int* in_sizes, int n_in,
                              void* d_out, int out_size, void* d_ws, size_t ws_size,
                              hipStream_t stream)
{
    const float2* x = (const float2*)d_in[0];
    float2* out     = (float2*)d_out;
    // 262144 float2 columns / 256 threads = 1024 blocks (4 blocks/CU, 16 waves/CU)
    TandemIF_86096914416163_kernel<<<dim3(NCOLS2 / 256), dim3(256), 0, stream>>>(x, out);
}